// Round 3
// baseline (169.723 us; speedup 1.0000x reference)
//
#include <hip/hip_runtime.h>
#include <math.h>

#define B_N 8192
#define D_N 512
#define S_N 5
#define C_N 2048
#define H_N 4
#define RB 16          // rows per mega block

typedef __attribute__((ext_vector_type(8))) short bf16x8;
typedef __attribute__((ext_vector_type(4))) float floatx4;

__device__ __forceinline__ float bf2f(short u) {
  union { unsigned int i; float f; } c;
  c.i = ((unsigned int)(unsigned short)u) << 16;
  return c.f;
}
__device__ __forceinline__ short f2bf(float f) {
  union { float f; unsigned int i; } c; c.f = f;
  unsigned int x = c.i;
  x += 0x7fffu + ((x >> 16) & 1u);   // round-to-nearest-even
  return (short)(x >> 16);
}
__device__ __forceinline__ unsigned long long pack4(float a, float b, float c, float d) {
  return (unsigned long long)(unsigned short)f2bf(a)
       | ((unsigned long long)(unsigned short)f2bf(b) << 16)
       | ((unsigned long long)(unsigned short)f2bf(c) << 32)
       | ((unsigned long long)(unsigned short)f2bf(d) << 48);
}

// ---------------- weight prep ----------------
// blocks 0..63:  WqT[n][k] = bf16(Wq[k][n])  via LDS tile transpose (coalesced both sides)
// blocks 64..95: Wkb = bf16(Wk) straight copy
__global__ __launch_bounds__(256) void k_prep(const float* __restrict__ Wq,
                                              const float* __restrict__ Wk,
                                              short* __restrict__ WqT,
                                              short* __restrict__ Wkb) {
  __shared__ float lds[64][65];
  const int bx = blockIdx.x, t = threadIdx.x;
  if (bx < 64) {
    const int r0 = (bx >> 3) * 64, c0 = (bx & 7) * 64;
#pragma unroll
    for (int i = 0; i < 16; ++i) {
      int r = i * 4 + (t >> 6), c = t & 63;
      lds[r][c] = Wq[(size_t)(r0 + r) * 512 + c0 + c];
    }
    __syncthreads();
#pragma unroll
    for (int i = 0; i < 16; ++i) {
      int cL = i * 4 + (t >> 6), rL = t & 63;
      WqT[(size_t)(c0 + cL) * 512 + r0 + rL] = f2bf(lds[rL][cL]);
    }
  } else {
    const int base = (bx - 64) * 8192 + t * 4;
#pragma unroll
    for (int i = 0; i < 8; ++i) {
      int idx = base + i * 1024;
      floatx4 v = *(const floatx4*)(Wk + idx);
      *(unsigned long long*)(Wkb + idx) = pack4(v[0], v[1], v[2], v[3]);
    }
  }
}

// ---------------- mega: everything else in ONE kernel ----------------
// grid 512 blocks x RB=16 rows, 256 threads (4 waves; wave w == head w), 2 blocks/CU
__global__ __launch_bounds__(256, 2) void k_mega(
    const float* __restrict__ f, const float* __restrict__ sf,
    const float* __restrict__ emb, const short* __restrict__ WqT,
    const short* __restrict__ Wkb, const float* __restrict__ bq,
    const float* __restrict__ bk, const float* __restrict__ logits,
    const float* __restrict__ temp, const float* __restrict__ attn_w,
    float* __restrict__ out, float* __restrict__ comb_out) {
  __shared__ __align__(16) float fLds[RB * 512];     // 32 KB, f32, XOR-swizzled rows
  __shared__ __align__(16) short Qbf[RB * 512];      // 16 KB, bf16, XOR-swizzled rows
  __shared__ __align__(16) short sfe[S_N * RB * 132];// 21120 B, pitch 264 B
  __shared__ float ffLds[RB];
  __shared__ float qtLds[RB][H_N];
  __shared__ float scLds[RB][H_N][S_N];
  __shared__ float fsLds[S_N][RB];
  __shared__ float ssLds[S_N][RB];
  __shared__ float combLds[RB][S_N];

  const int tid = threadIdx.x;
  const int lane = tid & 63;
  const int wid = tid >> 6;
  const int b0 = blockIdx.x * RB;
  const floatx4 fz = {0.f, 0.f, 0.f, 0.f};

  // ========= phase 0: f -> fLds (f32, swizzled) + ff =========
  {
    const int r0 = tid >> 4;
    const int c0 = (tid & 15) * 32;
    const float* fp = f + (size_t)(b0 + r0) * D_N + c0;
    char* fb = (char*)fLds;
    float ffp = 0.0f;
#pragma unroll
    for (int i = 0; i < 8; ++i) {
      floatx4 v = *(const floatx4*)(fp + i * 4);
      ffp += v[0]*v[0] + v[1]*v[1] + v[2]*v[2] + v[3]*v[3];
      int bo = (r0 * 2048 + (c0 + i * 4) * 4) ^ ((r0 & 7) << 4);
      *(floatx4*)(fb + bo) = v;
    }
    ffp += __shfl_xor(ffp, 1, 64);
    ffp += __shfl_xor(ffp, 2, 64);
    ffp += __shfl_xor(ffp, 4, 64);
    ffp += __shfl_xor(ffp, 8, 64);
    if ((tid & 15) == 0) ffLds[r0] = ffp;
  }
  __syncthreads();

  // ========= phase 1: Q = bf16(f) @ WqT (+bq); q~ = Q.bk; Q -> Qbf (swizzled) =========
  {
    const int wcol0 = wid * 128;
    floatx4 acc[8];
#pragma unroll
    for (int n = 0; n < 8; ++n) acc[n] = fz;
    const char* fb = (const char*)fLds;
    const int row = lane & 15;

    for (int ks = 0; ks < 16; ++ks) {
      bf16x8 bfr[8];
#pragma unroll
      for (int n = 0; n < 8; ++n) {
        int col = wcol0 + n * 16 + (lane & 15);
        bfr[n] = *(const bf16x8*)(WqT + (size_t)col * 512 + ks * 32 + (lane >> 4) * 8);
      }
      int kbase = ks * 32 + (lane >> 4) * 8;
      int bo0 = (row * 2048 + kbase * 4) ^ ((row & 7) << 4);
      int bo1 = (row * 2048 + kbase * 4 + 16) ^ ((row & 7) << 4);
      floatx4 a0 = *(const floatx4*)(fb + bo0);
      floatx4 a1 = *(const floatx4*)(fb + bo1);
      bf16x8 afr;
      afr[0] = f2bf(a0[0]); afr[1] = f2bf(a0[1]); afr[2] = f2bf(a0[2]); afr[3] = f2bf(a0[3]);
      afr[4] = f2bf(a1[0]); afr[5] = f2bf(a1[1]); afr[6] = f2bf(a1[2]); afr[7] = f2bf(a1[3]);
#pragma unroll
      for (int n = 0; n < 8; ++n)
        acc[n] = __builtin_amdgcn_mfma_f32_16x16x32_bf16(afr, bfr[n], acc[n], 0, 0, 0);
    }

    float bqv[8], bkv[8];
#pragma unroll
    for (int n = 0; n < 8; ++n) {
      int col = wcol0 + n * 16 + (lane & 15);
      bqv[n] = bq[col];
      bkv[n] = bk[col];
    }
#pragma unroll
    for (int j = 0; j < 4; ++j) {
      int orow = (lane >> 4) * 4 + j;
      float qp = 0.0f;
#pragma unroll
      for (int n = 0; n < 8; ++n) {
        float qv = acc[n][j] + bqv[n];
        int col = wcol0 + n * 16 + (lane & 15);
        int bo = (orow * 1024 + col * 2) ^ ((orow & 7) << 4);
        *(short*)((char*)Qbf + bo) = f2bf(qv);
        qp += qv * bkv[n];
      }
      qp += __shfl_xor(qp, 1, 64);
      qp += __shfl_xor(qp, 2, 64);
      qp += __shfl_xor(qp, 4, 64);
      qp += __shfl_xor(qp, 8, 64);
      if ((lane & 15) == 0) qtLds[orow][wid] = qp;
    }
  }
  __syncthreads();

  // ========= phase 2: 4 x 128-col chunks: stage sfe + ss/fs; R-MFMA + consume =========
  float scp[S_N][4];
#pragma unroll
  for (int s = 0; s < S_N; ++s)
#pragma unroll
    for (int j = 0; j < 4; ++j) scp[s][j] = 0.0f;
  float ssp[S_N] = {0, 0, 0, 0, 0}, fsp[S_N] = {0, 0, 0, 0, 0};

  const int h = wid;
  for (int cc = 0; cc < 4; ++cc) {
    // ---- 2a: stage sfe chunk (bf16) + ss/fs partials (f32; f from LDS) ----
    {
      const int r1 = tid >> 4;
      const int cs0 = (tid & 15) * 8;
      const int ac0 = cc * 128 + cs0;
      const char* fb = (const char*)fLds;
      int bo0 = (r1 * 2048 + ac0 * 4) ^ ((r1 & 7) << 4);
      int bo1 = (r1 * 2048 + ac0 * 4 + 16) ^ ((r1 & 7) << 4);
      floatx4 f0 = *(const floatx4*)(fb + bo0);
      floatx4 f1 = *(const floatx4*)(fb + bo1);
      float fv[8] = {f0[0], f0[1], f0[2], f0[3], f1[0], f1[1], f1[2], f1[3]};
#pragma unroll
      for (int s = 0; s < S_N; ++s) {
        const float* sp = sf + ((size_t)s * B_N + b0 + r1) * D_N + ac0;
        floatx4 s0 = *(const floatx4*)(sp);
        floatx4 s1 = *(const floatx4*)(sp + 4);
        const float* ep = emb + s * D_N + ac0;
        floatx4 e0 = *(const floatx4*)(ep);
        floatx4 e1 = *(const floatx4*)(ep + 4);
        float sv[8] = {s0[0], s0[1], s0[2], s0[3], s1[0], s1[1], s1[2], s1[3]};
        float se[8] = {s0[0]+e0[0], s0[1]+e0[1], s0[2]+e0[2], s0[3]+e0[3],
                       s1[0]+e1[0], s1[1]+e1[1], s1[2]+e1[2], s1[3]+e1[3]};
        float ssl = 0.0f, fsl = 0.0f;
#pragma unroll
        for (int q = 0; q < 8; ++q) { ssl += sv[q] * sv[q]; fsl += fv[q] * sv[q]; }
        ssp[s] += ssl; fsp[s] += fsl;
        int rowbase = (s * RB + r1) * 264 + cs0 * 2;
        *(unsigned long long*)((char*)sfe + rowbase)     = pack4(se[0], se[1], se[2], se[3]);
        *(unsigned long long*)((char*)sfe + rowbase + 8) = pack4(se[4], se[5], se[6], se[7]);
      }
    }
    __syncthreads();

    // ---- 2b: R chunk = Q(head h) @ Wk^T; consume with sfe ----
    {
      floatx4 acc2[8];
#pragma unroll
      for (int n = 0; n < 8; ++n) acc2[n] = fz;
      const int row = lane & 15;
#pragma unroll
      for (int ks = 0; ks < 4; ++ks) {
        bf16x8 bfr[8];
#pragma unroll
        for (int n = 0; n < 8; ++n) {
          int a = cc * 128 + n * 16 + (lane & 15);
          bfr[n] = *(const bf16x8*)(Wkb + (size_t)a * 512 + h * 128 + ks * 32 + (lane >> 4) * 8);
        }
        int bo = (row * 1024 + (h * 128 + ks * 32 + (lane >> 4) * 8) * 2) ^ ((row & 7) << 4);
        bf16x8 afr = *(const bf16x8*)((const char*)Qbf + bo);
#pragma unroll
        for (int n = 0; n < 8; ++n)
          acc2[n] = __builtin_amdgcn_mfma_f32_16x16x32_bf16(afr, bfr[n], acc2[n], 0, 0, 0);
      }
#pragma unroll
      for (int s = 0; s < S_N; ++s) {
#pragma unroll
        for (int j = 0; j < 4; ++j) {
          int orow = (lane >> 4) * 4 + j;
          int base = (s * RB + orow) * 264 + (lane & 15) * 2;
          float p = 0.0f;
#pragma unroll
          for (int n = 0; n < 8; ++n) {
            short svv = *(const short*)((const char*)sfe + base + n * 32);
            p += acc2[n][j] * bf2f(svv);
          }
          scp[s][j] += p;
        }
      }
    }
    __syncthreads();
  }

  // ========= phase 3: reductions + finalize combined =========
#pragma unroll
  for (int s = 0; s < S_N; ++s)
#pragma unroll
    for (int j = 0; j < 4; ++j) {
      float v = scp[s][j];
      v += __shfl_xor(v, 1, 64);
      v += __shfl_xor(v, 2, 64);
      v += __shfl_xor(v, 4, 64);
      v += __shfl_xor(v, 8, 64);
      if ((lane & 15) == 0) scLds[(lane >> 4) * 4 + j][wid][s] = v;
    }
  {
    const int r1 = tid >> 4;
#pragma unroll
    for (int s = 0; s < S_N; ++s) {
      float u = ssp[s], v = fsp[s];
      u += __shfl_xor(u, 1, 64); v += __shfl_xor(v, 1, 64);
      u += __shfl_xor(u, 2, 64); v += __shfl_xor(v, 2, 64);
      u += __shfl_xor(u, 4, 64); v += __shfl_xor(v, 4, 64);
      u += __shfl_xor(u, 8, 64); v += __shfl_xor(v, 8, 64);
      if ((tid & 15) == 0) { ssLds[s][r1] = u; fsLds[s][r1] = v; }
    }
  }
  __syncthreads();

  if (tid < RB) {
    const int r = tid;
    const float ffv = ffLds[r];
    const float t = fabsf(temp[0]);

    float amha[S_N] = {0, 0, 0, 0, 0};
    const float inv_mha = 1.0f / (sqrtf(128.0f) * t);
#pragma unroll
    for (int hh = 0; hh < H_N; ++hh) {
      float lg[S_N];
#pragma unroll
      for (int s = 0; s < S_N; ++s) lg[s] = (scLds[r][hh][s] + qtLds[r][hh]) * inv_mha;
      float mx = lg[0];
#pragma unroll
      for (int s = 1; s < S_N; ++s) mx = fmaxf(mx, lg[s]);
      float e[S_N], sum = 0;
#pragma unroll
      for (int s = 0; s < S_N; ++s) { e[s] = __expf(lg[s] - mx); sum += e[s]; }
      float isum = 0.25f / sum;
#pragma unroll
      for (int s = 0; s < S_N; ++s) amha[s] += e[s] * isum;
    }

    float ageo[S_N];
    {
      const float nf = fmaxf(sqrtf(ffv), 1e-12f);
      float g[S_N];
#pragma unroll
      for (int s = 0; s < S_N; ++s) {
        float ns = fmaxf(sqrtf(ssLds[s][r]), 1e-12f);
        float cs0 = fsLds[s][r] / (nf * ns);
        cs0 = fminf(fmaxf(cs0, -1.0f + 1e-7f), 1.0f - 1e-7f);
        g[s] = __expf(-acosf(cs0) / t);
      }
      float mx = g[0];
#pragma unroll
      for (int s = 1; s < S_N; ++s) mx = fmaxf(mx, g[s]);
      float sum = 0;
#pragma unroll
      for (int s = 0; s < S_N; ++s) { ageo[s] = __expf(g[s] - mx); sum += ageo[s]; }
#pragma unroll
      for (int s = 0; s < S_N; ++s) ageo[s] /= sum;
    }

    float acay[S_N];
    {
      const float SQ2 = 1.41421356237309515f;
      const float Aff = 0.72f;
      const float Ass = 0.72f - 0.32f * SQ2;
      const float Afs = -(8.0f + 4.0f * SQ2) / 25.0f;
      float lg[S_N];
#pragma unroll
      for (int s = 0; s < S_N; ++s)
        lg[s] = (Aff * ffv + Ass * ssLds[s][r] + Afs * fsLds[s][r]) / t;
      float mx = lg[0];
#pragma unroll
      for (int s = 1; s < S_N; ++s) mx = fmaxf(mx, lg[s]);
      float sum = 0;
#pragma unroll
      for (int s = 0; s < S_N; ++s) { acay[s] = __expf(lg[s] - mx); sum += acay[s]; }
#pragma unroll
      for (int s = 0; s < S_N; ++s) acay[s] /= sum;
    }

    float w0 = attn_w[0], w1 = attn_w[1], w2 = attn_w[2];
    float wm = fmaxf(w0, fmaxf(w1, w2));
    float e0 = __expf(w0 - wm), e1 = __expf(w1 - wm), e2 = __expf(w2 - wm);
    float wsum = e0 + e1 + e2;
    w0 = e0 / wsum; w1 = e1 / wsum; w2 = e2 / wsum;

    float cb[S_N], csum = 0;
#pragma unroll
    for (int s = 0; s < S_N; ++s) {
      cb[s] = w0 * amha[s] + w1 * ageo[s] + w2 * acay[s];
      csum += cb[s];
    }
    float ic = 1.0f / csum;
#pragma unroll
    for (int s = 0; s < S_N; ++s) {
      float cv = cb[s] * ic;
      combLds[r][s] = cv;
      comb_out[(size_t)(b0 + r) * S_N + s] = cv;
    }
  }
  __syncthreads();

  // ========= phase 4: fused logits mix: out[b,c] = sum_s comb[b,s]*logits[s,b,c] =========
  {
    const int c0 = tid * 8;
#pragma unroll 2
    for (int r = 0; r < RB; r += 2) {
      float cA[S_N], cB[S_N];
#pragma unroll
      for (int s = 0; s < S_N; ++s) { cA[s] = combLds[r][s]; cB[s] = combLds[r + 1][s]; }
      floatx4 aA = fz, aB = fz, bA = fz, bB = fz;
#pragma unroll
      for (int s = 0; s < S_N; ++s) {
        const float* lpA = logits + ((size_t)s * B_N + b0 + r) * C_N + c0;
        floatx4 xA0 = *(const floatx4*)(lpA);
        floatx4 xA1 = *(const floatx4*)(lpA + 4);
        floatx4 xB0 = *(const floatx4*)(lpA + C_N);
        floatx4 xB1 = *(const floatx4*)(lpA + C_N + 4);
        aA += xA0 * cA[s]; aB += xA1 * cA[s];
        bA += xB0 * cB[s]; bB += xB1 * cB[s];
      }
      float* opA = out + (size_t)(b0 + r) * C_N + c0;
      *(floatx4*)(opA) = aA;
      *(floatx4*)(opA + 4) = aB;
      *(floatx4*)(opA + C_N) = bA;
      *(floatx4*)(opA + C_N + 4) = bB;
    }
  }
}

extern "C" void kernel_launch(void* const* d_in, const int* in_sizes, int n_in,
                              void* d_out, int out_size, void* d_ws, size_t ws_size,
                              hipStream_t stream) {
  const float* features = (const float*)d_in[0];
  const float* logits   = (const float*)d_in[1];
  const float* sf       = (const float*)d_in[2];
  const float* Wq       = (const float*)d_in[3];
  const float* bq       = (const float*)d_in[4];
  const float* Wk       = (const float*)d_in[5];
  const float* bk       = (const float*)d_in[6];
  const float* emb      = (const float*)d_in[9];
  const float* temp     = (const float*)d_in[10];
  const float* attn_w   = (const float*)d_in[11];

  float* out  = (float*)d_out;
  float* comb = out + (size_t)B_N * C_N;

  char* w = (char*)d_ws;
  short* WqT = (short*)(w);                    // 512*512 bf16 = 0.52 MB
  short* Wkb = (short*)(w + 524288);           // 512*512 bf16 = 0.52 MB

  // 1. weights -> bf16 (WqT transposed, coalesced via LDS tiles)
  k_prep<<<dim3(96), dim3(256), 0, stream>>>(Wq, Wk, WqT, Wkb);
  // 2. everything else fused: cvt + Q + R + scores + stats + softmaxes + logits mix
  k_mega<<<dim3(512), dim3(256), 0, stream>>>(features, sf, emb, WqT, Wkb, bq, bk,
                                              logits, temp, attn_w, out, comb);
}

// Round 5
// 159.020 us; speedup vs baseline: 1.0673x; 1.0673x over previous
//
#include <hip/hip_runtime.h>
#include <math.h>

#define B_N 8192
#define D_N 512
#define S_N 5
#define C_N 2048
#define H_N 4

typedef __attribute__((ext_vector_type(8))) short bf16x8;
typedef __attribute__((ext_vector_type(4))) float floatx4;

__device__ __forceinline__ float bf2f(short u) {
  union { unsigned int i; float f; } c;
  c.i = ((unsigned int)(unsigned short)u) << 16;
  return c.f;
}
__device__ __forceinline__ short f2bf(float f) {
  union { float f; unsigned int i; } c; c.f = f;
  unsigned int x = c.i;
  x += 0x7fffu + ((x >> 16) & 1u);   // round-to-nearest-even
  return (short)(x >> 16);
}
__device__ __forceinline__ unsigned long long pack4(float a, float b, float c, float d) {
  return (unsigned long long)(unsigned short)f2bf(a)
       | ((unsigned long long)(unsigned short)f2bf(b) << 16)
       | ((unsigned long long)(unsigned short)f2bf(c) << 32)
       | ((unsigned long long)(unsigned short)f2bf(d) << 48);
}

// ---------------- f -> bf16 (round-1 verbatim, passed) ----------------
__global__ __launch_bounds__(256) void k_cvt_f(const float* __restrict__ f,
                                               short* __restrict__ fbf, int n8) {
  int i = blockIdx.x * 256 + threadIdx.x;
  if (i >= n8) return;
  const floatx4* p = (const floatx4*)(f + (size_t)i * 8);
  floatx4 a = p[0], b = p[1];
  bf16x8 o;
  o[0] = f2bf(a[0]); o[1] = f2bf(a[1]); o[2] = f2bf(a[2]); o[3] = f2bf(a[3]);
  o[4] = f2bf(b[0]); o[5] = f2bf(b[1]); o[6] = f2bf(b[2]); o[7] = f2bf(b[3]);
  *(bf16x8*)(fbf + (size_t)i * 8) = o;
}

// ---------------- weight prep (round-3 verbatim, passed) ----------------
__global__ __launch_bounds__(256) void k_prep(const float* __restrict__ Wq,
                                              const float* __restrict__ Wk,
                                              short* __restrict__ WqT,
                                              short* __restrict__ Wkb) {
  __shared__ float lds[64][65];
  const int bx = blockIdx.x, t = threadIdx.x;
  if (bx < 64) {
    const int r0 = (bx >> 3) * 64, c0 = (bx & 7) * 64;
#pragma unroll
    for (int i = 0; i < 16; ++i) {
      int r = i * 4 + (t >> 6), c = t & 63;
      lds[r][c] = Wq[(size_t)(r0 + r) * 512 + c0 + c];
    }
    __syncthreads();
#pragma unroll
    for (int i = 0; i < 16; ++i) {
      int cL = i * 4 + (t >> 6), rL = t & 63;
      WqT[(size_t)(c0 + cL) * 512 + r0 + rL] = f2bf(lds[rL][cL]);
    }
  } else {
    const int base = (bx - 64) * 8192 + t * 4;
#pragma unroll
    for (int i = 0; i < 8; ++i) {
      int idx = base + i * 1024;
      floatx4 v = *(const floatx4*)(Wk + idx);
      *(unsigned long long*)(Wkb + idx) = pack4(v[0], v[1], v[2], v[3]);
    }
  }
}

// ---------------- MFMA GEMM (round-1 verbatim, passed) ----------------
__device__ __forceinline__ void gll(const short* g, short* l) {
  __builtin_amdgcn_global_load_lds(
      (const __attribute__((address_space(1))) unsigned int*)(g),
      (__attribute__((address_space(3))) unsigned int*)(l), 16, 0, 0);
}

__global__ __launch_bounds__(256) void k_gemm(
    const short* __restrict__ A, int lda,
    const short* __restrict__ BT, int ldb,
    short* __restrict__ O, int ldo,
    const float* __restrict__ bias, int K, int z_koff, int z_coff) {
  __shared__ __align__(16) short As[2][4096];
  __shared__ __align__(16) short Bs[2][4096];

  const int tid = threadIdx.x;
  const int lane = tid & 63;
  const int wid = tid >> 6;
  const int wr = wid >> 1, wc = wid & 1;
  const int row0 = blockIdx.y * 128;
  const int col0 = blockIdx.x * 128;
  const int z = blockIdx.z;
  const int koff = z * z_koff;
  const int ocoff = z * z_coff;

  const int r1 = tid >> 2, hk = tid & 3;
  const short* Ag1 = A + (size_t)(row0 + r1) * lda + koff + hk * 8;
  const short* Ag2 = A + (size_t)(row0 + 64 + r1) * lda + koff + hk * 8;
  const short* Bg1 = BT + (size_t)(col0 + r1) * ldb + koff + hk * 8;
  const short* Bg2 = BT + (size_t)(col0 + 64 + r1) * ldb + koff + hk * 8;

  floatx4 acc[4][4];
  const floatx4 zero = {0.0f, 0.0f, 0.0f, 0.0f};
#pragma unroll
  for (int m = 0; m < 4; ++m)
#pragma unroll
    for (int n = 0; n < 4; ++n) acc[m][n] = zero;

  const int NT = K >> 5;
  int cur = 0;

  auto stage = [&](int q, int kb) {
    gll(Ag1 + kb, &As[q][tid * 8]);
    gll(Ag2 + kb, &As[q][tid * 8 + 2048]);
    gll(Bg1 + kb, &Bs[q][tid * 8]);
    gll(Bg2 + kb, &Bs[q][tid * 8 + 2048]);
  };

  stage(0, 0);
  __syncthreads();

  for (int t = 0; t < NT; ++t) {
    if (t + 1 < NT) stage(cur ^ 1, (t + 1) * 32);
    bf16x8 af[4], bfr[4];
#pragma unroll
    for (int m = 0; m < 4; ++m)
      af[m] = *(const bf16x8*)&As[cur][(wr * 64 + m * 16 + (lane & 15)) * 32 + (lane >> 4) * 8];
#pragma unroll
    for (int n = 0; n < 4; ++n)
      bfr[n] = *(const bf16x8*)&Bs[cur][(wc * 64 + n * 16 + (lane & 15)) * 32 + (lane >> 4) * 8];
#pragma unroll
    for (int m = 0; m < 4; ++m)
#pragma unroll
      for (int n = 0; n < 4; ++n)
        acc[m][n] = __builtin_amdgcn_mfma_f32_16x16x32_bf16(af[m], bfr[n], acc[m][n], 0, 0, 0);
    __syncthreads();
    cur ^= 1;
  }

#pragma unroll
  for (int m = 0; m < 4; ++m) {
    int rowb = row0 + wr * 64 + m * 16 + (lane >> 4) * 4;
#pragma unroll
    for (int n = 0; n < 4; ++n) {
      int lcol = col0 + wc * 64 + n * 16 + (lane & 15);
      float bv = bias ? bias[lcol] : 0.0f;
      int ocol = ocoff + lcol;
#pragma unroll
      for (int j = 0; j < 4; ++j) {
        O[(size_t)(rowb + j) * ldo + ocol] = f2bf(acc[m][n][j] + bv);
      }
    }
  }
}

// ---------------- fused stats + attention + logits mix (1 wave per row) ----------------
// grid 2048 x 256 thr; wave w -> row b = blockIdx*4 + w. ZERO LDS, ZERO barriers.
__global__ __launch_bounds__(256, 4) void k_fused(
    const float* __restrict__ f, const float* __restrict__ sf,
    const float* __restrict__ emb, const short* __restrict__ Qbf,
    const short* __restrict__ Rbf, const float* __restrict__ bk,
    const float* __restrict__ temp, const float* __restrict__ attn_w,
    const float* __restrict__ logits, float* __restrict__ out,
    float* __restrict__ comb_out) {
  const int lane = threadIdx.x & 63;
  const int wid = threadIdx.x >> 6;
  const int b = blockIdx.x * 4 + wid;
  const int a0 = lane * 8;

  // ---- stats (round-1 k_stats verbatim) ----
  const floatx4* fp = (const floatx4*)(f + (size_t)b * D_N + a0);
  floatx4 fA = fp[0], fB = fp[1];
  float fv[8];
#pragma unroll
  for (int j = 0; j < 4; ++j) { fv[j] = fA[j]; fv[4 + j] = fB[j]; }
  float ffp = 0;
#pragma unroll
  for (int j = 0; j < 8; ++j) ffp += fv[j] * fv[j];

  bf16x8 qv = *(const bf16x8*)(Qbf + (size_t)b * D_N + a0);
  float qbkp = 0;
#pragma unroll
  for (int j = 0; j < 8; ++j) qbkp += bf2f(qv[j]) * bk[a0 + j];

  float rf[H_N][8];
#pragma unroll
  for (int h = 0; h < H_N; ++h) {
    bf16x8 rv = *(const bf16x8*)(Rbf + (size_t)b * 2048 + h * 512 + a0);
#pragma unroll
    for (int j = 0; j < 8; ++j) rf[h][j] = bf2f(rv[j]);
  }

  const int myh = lane >> 4;
  float fs_[S_N], ss_[S_N], sc_[S_N][H_N];

#pragma unroll
  for (int s = 0; s < S_N; ++s) {
    const floatx4* sp = (const floatx4*)(sf + ((size_t)s * B_N + b) * D_N + a0);
    floatx4 sA = sp[0], sB = sp[1];
    const floatx4* ep = (const floatx4*)(emb + (size_t)s * D_N + a0);
    floatx4 eA = ep[0], eB = ep[1];
    float sv[8], se[8];
#pragma unroll
    for (int j = 0; j < 4; ++j) {
      sv[j] = sA[j]; sv[4 + j] = sB[j];
      se[j] = sA[j] + eA[j]; se[4 + j] = sB[j] + eB[j];
    }
    float fsp = 0, ssp = 0;
    float scp[H_N];
#pragma unroll
    for (int h = 0; h < H_N; ++h) scp[h] = (myh == h) ? qbkp : 0.0f;
#pragma unroll
    for (int j = 0; j < 8; ++j) {
      fsp += fv[j] * sv[j];
      ssp += sv[j] * sv[j];
#pragma unroll
      for (int h = 0; h < H_N; ++h) scp[h] += se[j] * rf[h][j];
    }
#pragma unroll
    for (int o = 1; o < 64; o <<= 1) {
      fsp += __shfl_xor(fsp, o, 64);
      ssp += __shfl_xor(ssp, o, 64);
#pragma unroll
      for (int h = 0; h < H_N; ++h) scp[h] += __shfl_xor(scp[h], o, 64);
    }
    fs_[s] = fsp; ss_[s] = ssp;
#pragma unroll
    for (int h = 0; h < H_N; ++h) sc_[s][h] = scp[h];
  }
  float ffv = ffp;
#pragma unroll
  for (int o = 1; o < 64; o <<= 1) ffv += __shfl_xor(ffv, o, 64);

  // ---- finalize (all lanes redundantly, wave-uniform; round-1 verbatim) ----
  const float t = fabsf(temp[0]);

  float amha[S_N] = {0, 0, 0, 0, 0};
  const float inv_mha = 1.0f / (sqrtf(128.0f) * t);
#pragma unroll
  for (int h = 0; h < H_N; ++h) {
    float lg[S_N];
#pragma unroll
    for (int s = 0; s < S_N; ++s) lg[s] = sc_[s][h] * inv_mha;
    float mx = lg[0];
#pragma unroll
    for (int s = 1; s < S_N; ++s) mx = fmaxf(mx, lg[s]);
    float e[S_N], sum = 0;
#pragma unroll
    for (int s = 0; s < S_N; ++s) { e[s] = __expf(lg[s] - mx); sum += e[s]; }
    float isum = 0.25f / sum;
#pragma unroll
    for (int s = 0; s < S_N; ++s) amha[s] += e[s] * isum;
  }

  float ageo[S_N];
  {
    const float nf = fmaxf(sqrtf(ffv), 1e-12f);
    float g[S_N];
#pragma unroll
    for (int s = 0; s < S_N; ++s) {
      float ns = fmaxf(sqrtf(ss_[s]), 1e-12f);
      float cs0 = fs_[s] / (nf * ns);
      cs0 = fminf(fmaxf(cs0, -1.0f + 1e-7f), 1.0f - 1e-7f);
      g[s] = __expf(-acosf(cs0) / t);
    }
    float mx = g[0];
#pragma unroll
    for (int s = 1; s < S_N; ++s) mx = fmaxf(mx, g[s]);
    float sum = 0;
#pragma unroll
    for (int s = 0; s < S_N; ++s) { ageo[s] = __expf(g[s] - mx); sum += ageo[s]; }
#pragma unroll
    for (int s = 0; s < S_N; ++s) ageo[s] /= sum;
  }

  float acay[S_N];
  {
    const float SQ2 = 1.41421356237309515f;
    const float Aff = 0.72f;
    const float Ass = 0.72f - 0.32f * SQ2;
    const float Afs = -(8.0f + 4.0f * SQ2) / 25.0f;
    float lg[S_N];
#pragma unroll
    for (int s = 0; s < S_N; ++s)
      lg[s] = (Aff * ffv + Ass * ss_[s] + Afs * fs_[s]) / t;
    float mx = lg[0];
#pragma unroll
    for (int s = 1; s < S_N; ++s) mx = fmaxf(mx, lg[s]);
    float sum = 0;
#pragma unroll
    for (int s = 0; s < S_N; ++s) { acay[s] = __expf(lg[s] - mx); sum += acay[s]; }
#pragma unroll
    for (int s = 0; s < S_N; ++s) acay[s] /= sum;
  }

  float w0 = attn_w[0], w1 = attn_w[1], w2 = attn_w[2];
  float wm = fmaxf(w0, fmaxf(w1, w2));
  float e0 = __expf(w0 - wm), e1 = __expf(w1 - wm), e2 = __expf(w2 - wm);
  float wsum = e0 + e1 + e2;
  w0 = e0 / wsum; w1 = e1 / wsum; w2 = e2 / wsum;

  float cb[S_N], csum = 0;
#pragma unroll
  for (int s = 0; s < S_N; ++s) {
    cb[s] = w0 * amha[s] + w1 * ageo[s] + w2 * acay[s];
    csum += cb[s];
  }
  float ic = 1.0f / csum;
  float cbn[S_N];
#pragma unroll
  for (int s = 0; s < S_N; ++s) cbn[s] = cb[s] * ic;
  if (lane == 0) {
#pragma unroll
    for (int s = 0; s < S_N; ++s) comb_out[(size_t)b * S_N + s] = cbn[s];
  }

  // ---- mix tail (round-1 k_mix math, per-wave; cbn live in registers) ----
  const floatx4 fz = {0.f, 0.f, 0.f, 0.f};
#pragma unroll
  for (int cj = 0; cj < 4; ++cj) {
    const int c0 = cj * 512 + lane * 8;
    floatx4 accA = fz, accB = fz;
#pragma unroll
    for (int s = 0; s < S_N; ++s) {
      const float* lp = logits + ((size_t)s * B_N + b) * C_N + c0;
      floatx4 lA = *(const floatx4*)lp;
      floatx4 lB = *(const floatx4*)(lp + 4);
      accA += lA * cbn[s];
      accB += lB * cbn[s];
    }
    float* op = out + (size_t)b * C_N + c0;
    *(floatx4*)op = accA;
    *(floatx4*)(op + 4) = accB;
  }
}

extern "C" void kernel_launch(void* const* d_in, const int* in_sizes, int n_in,
                              void* d_out, int out_size, void* d_ws, size_t ws_size,
                              hipStream_t stream) {
  const float* features = (const float*)d_in[0];
  const float* logits   = (const float*)d_in[1];
  const float* sf       = (const float*)d_in[2];
  const float* Wq       = (const float*)d_in[3];
  const float* bq       = (const float*)d_in[4];
  const float* Wk       = (const float*)d_in[5];
  const float* bk       = (const float*)d_in[6];
  const float* emb      = (const float*)d_in[9];
  const float* temp     = (const float*)d_in[10];
  const float* attn_w   = (const float*)d_in[11];

  float* out  = (float*)d_out;
  float* comb = out + (size_t)B_N * C_N;

  char* w = (char*)d_ws;
  short* fbf = (short*)(w);                    // 8192*512  bf16 =  8.39 MB
  short* Qbf = (short*)(w + 8388608);          // 8192*512  bf16 =  8.39 MB
  short* Rbf = (short*)(w + 16777216);         // 8192*2048 bf16 = 33.55 MB
  short* WqT = (short*)(w + 50331648);         // 512*512   bf16 =  0.52 MB
  short* Wkb = (short*)(w + 50855936);         // 512*512   bf16 =  0.52 MB

  // 1. f -> bf16
  k_cvt_f<<<dim3(2048), dim3(256), 0, stream>>>(features, fbf, 524288);
  // 2. weights -> bf16 (WqT transposed)
  k_prep<<<dim3(96), dim3(256), 0, stream>>>(Wq, Wk, WqT, Wkb);
  // 3. Q = f @ Wq + bq
  k_gemm<<<dim3(4, 64, 1), dim3(256), 0, stream>>>(fbf, 512, WqT, 512, Qbf, 512,
                                                   bq, 512, 0, 0);
  // 4. R[b, h*512+a] = sum_j Q[b,h*128+j] * Wk[a,h*128+j]
  k_gemm<<<dim3(4, 64, 4), dim3(256), 0, stream>>>(Qbf, 512, Wkb, 512, Rbf, 2048,
                                                   (const float*)nullptr, 128, 128, 512);
  // 5. fused stats + attentions + fuse + logits mix (1 wave per row, no LDS/barriers)
  k_fused<<<dim3(2048), dim3(256), 0, stream>>>(features, sf, emb, Qbf, Rbf, bk,
                                                temp, attn_w, logits, out, comb);
}